// Round 5
// baseline (836.548 us; speedup 1.0000x reference)
//
#include <hip/hip_runtime.h>
#include <stddef.h>

typedef __attribute__((ext_vector_type(8))) short bf16x8;   // MFMA A/B frag
typedef __attribute__((ext_vector_type(4))) float f32x4;    // MFMA C/D frag
typedef __attribute__((ext_vector_type(8))) float f32x8;    // 32B fp32 load

#define NPB 512            // nodes per bucket (power of 2: bucket = c >> 9)
#define PB  512            // scatter blocks

// ---------------------------------------------------------------------------
// Manual bf16 <-> fp32 (storage type = unsigned short)
// ---------------------------------------------------------------------------
__device__ inline float bf2f(unsigned short u) {
    unsigned int v = ((unsigned int)u) << 16;
    float f;
    __builtin_memcpy(&f, &v, 4);
    return f;
}
__device__ inline unsigned short f2bf(float f) {
    unsigned int v;
    __builtin_memcpy(&v, &f, 4);
    unsigned int r = (v + 0x7FFFu + ((v >> 16) & 1u)) >> 16;   // RNE
    return (unsigned short)r;
}
__device__ inline float feat(const void* p, long long idx, int isbf) {
    if (isbf) return bf2f(((const unsigned short*)p)[idx]);
    return ((const float*)p)[idx];
}
__device__ inline int clampi(int v, int lo, int hi) {
    return v < lo ? lo : (v > hi ? hi : v);
}

// ---------------------------------------------------------------------------
// Format detection. flags[0]=edge_index int64; flags[1]=edge_weight bf16;
// flags[2]=features bf16; flags[3]=all edge_weights == 1.0.
// ---------------------------------------------------------------------------
__global__ void detect_kernel(const int* ei, const unsigned short* ew16,
                              const unsigned short* x16, int* flags) {
    __shared__ int s_is64, s_pass;
    if (threadIdx.x == 0) { s_is64 = 1; s_pass = 0; }
    __syncthreads();
    int t = threadIdx.x;
    if (t < 128 && ei[2 * t + 1] != 0) atomicAnd(&s_is64, 0);
    if (t < 64) {
        unsigned short h = x16[t];
        unsigned int expf = (h >> 7) & 0xFF;
        if (h == 0 || (expf >= 112 && expf <= 142)) atomicAdd(&s_pass, 1);
    }
    __syncthreads();
    if (t == 0) {
        flags[0] = s_is64;
        flags[1] = (ew16[0] == 0x3F80) ? 1 : 0;
        flags[2] = (s_pass >= 56) ? 1 : 0;
        flags[3] = 1;
    }
}

__global__ void ones_kernel(const void* ew, int* flags, int E) {
    int i = blockIdx.x * blockDim.x + threadIdx.x;
    int wbf = flags[1];
    int b = i * 4;
    int lim = b + 4 < E ? b + 4 : E;
    bool bad = false;
    for (int k = b; k < lim; k++)
        if (feat(ew, k, wbf) != 1.0f) bad = true;
    if (bad) atomicAnd(&flags[3], 0);
}

__global__ void sentinel_kernel(unsigned short* outp, int n, float val) {
    int i = blockIdx.x * blockDim.x + threadIdx.x;
    if (i < n) outp[i] = f2bf(val);
}

// ---------------------------------------------------------------------------
// One-time weight split: W (fp32 or bf16) -> (Whi, Wlo) bf16 pair.
// fp32: v ~= hi + lo; bf16 input: hi = v, lo = 0. Zero-pads to n_out.
// ---------------------------------------------------------------------------
__global__ void wsplit_kernel(const void* W, const int* flags, unsigned short* hi,
                              unsigned short* lo, int n_in, int n_out) {
    int i = blockIdx.x * blockDim.x + threadIdx.x;
    if (i >= n_out) return;
    if (i >= n_in) { hi[i] = 0; lo[i] = 0; return; }
    if (flags[2]) {
        hi[i] = ((const unsigned short*)W)[i];
        lo[i] = 0;
    } else {
        float v = ((const float*)W)[i];
        unsigned short h = f2bf(v);
        hi[i] = h;
        lo[i] = f2bf(v - bf2f(h));
    }
}

// ---------------------------------------------------------------------------
// Bucketed CSR build (atomic-light; all heavy writes locality-grouped)
// ---------------------------------------------------------------------------
// K1: per-block bucket histograms (LDS atomics only)
__global__ __launch_bounds__(512) void khist_kernel(const int* ei, const int* flags,
                                                    int* ghist, int E, int n,
                                                    int NB, int chunk) {
    __shared__ int hist[256];
    int blk = blockIdx.x;
    for (int i = threadIdx.x; i < NB; i += blockDim.x) hist[i] = 0;
    __syncthreads();
    int is64 = flags[0];
    int e0 = blk * chunk;
    int e1 = e0 + chunk < E ? e0 + chunk : E;
    for (int e = e0 + (int)threadIdx.x; e < e1; e += blockDim.x) {
        int c = is64 ? ei[2 * (E + e)] : ei[E + e];
        c = clampi(c, 0, n - 1);
        atomicAdd(&hist[c >> 9], 1);
    }
    __syncthreads();
    for (int i = threadIdx.x; i < NB; i += blockDim.x) ghist[blk * NB + i] = hist[i];
}

// K2: per-bucket exclusive scan over the PB block histograms (in place) + totals
__global__ __launch_bounds__(512) void koff1_kernel(int* ghist, int* btot, int NB) {
    __shared__ int s[512];
    int b = blockIdx.x;
    int t = threadIdx.x;
    int v = ghist[t * NB + b];
    s[t] = v;
    __syncthreads();
    for (int off = 1; off < 512; off <<= 1) {
        int add = (t >= off) ? s[t - off] : 0;
        __syncthreads();
        s[t] += add;
        __syncthreads();
    }
    ghist[t * NB + b] = s[t] - v;              // exclusive
    if (t == 511) btot[b] = s[511];
}

// K3: scan bucket totals -> bstart; write row_ptr[N] = E
__global__ __launch_bounds__(256) void koff2_kernel(const int* btot, int* bstart,
                                                    int* row_ptr, int NB, int N, int E) {
    __shared__ int s[256];
    int t = threadIdx.x;
    int v = (t < NB) ? btot[t] : 0;
    s[t] = v;
    __syncthreads();
    for (int off = 1; off < 256; off <<= 1) {
        int add = (t >= off) ? s[t - off] : 0;
        __syncthreads();
        s[t] += add;
        __syncthreads();
    }
    if (t < NB) bstart[t] = s[t] - v;
    if (t == 0) row_ptr[N] = E;
}

// K4: scatter edges into bucket-grouped ebuf (pack: c_local<<17 | r), deterministic
// offsets (no global atomics). wbuf written only on the general-weight path.
__global__ __launch_bounds__(512) void kscatter_kernel(const int* ei, const void* ew,
                                                       const int* flags, const int* ghist,
                                                       const int* bstart,
                                                       unsigned int* ebuf, float* wbuf,
                                                       int E, int n, int NB, int chunk) {
    __shared__ int cur[256];
    int blk = blockIdx.x;
    for (int i = threadIdx.x; i < NB; i += blockDim.x)
        cur[i] = ghist[blk * NB + i] + bstart[i];
    __syncthreads();
    int is64 = flags[0], wbf = flags[1], ones = flags[3];
    int e0 = blk * chunk;
    int e1 = e0 + chunk < E ? e0 + chunk : E;
    for (int e = e0 + (int)threadIdx.x; e < e1; e += blockDim.x) {
        int r = is64 ? ei[2 * e] : ei[e];
        int c = is64 ? ei[2 * (E + e)] : ei[E + e];
        r = clampi(r, 0, n - 1);
        c = clampi(c, 0, n - 1);
        int b = c >> 9;
        int pos = atomicAdd(&cur[b], 1);       // LDS atomic
        ebuf[pos] = ((unsigned int)(c & 511) << 17) | (unsigned int)r;
        if (!ones) wbuf[pos] = feat(ew, e, wbf);
    }
}

// K5: per-bucket node counts -> row_ptr + dinv (no global atomics)
__global__ __launch_bounds__(512) void kcsr_a_kernel(const unsigned int* ebuf,
                                                     const float* wbuf, const int* flags,
                                                     const int* bstart, const int* btot,
                                                     int* row_ptr, float* dinv, int N) {
    __shared__ int cnt[512];
    __shared__ int pre[512];
    __shared__ float wsum[512];
    int b = blockIdx.x;
    int t = threadIdx.x;
    int ones = flags[3];
    cnt[t] = 0;
    wsum[t] = 0.f;
    __syncthreads();
    int bs = bstart[b];
    int be = bs + btot[b];
    for (int i = bs + t; i < be; i += 512) {
        unsigned int p = ebuf[i];
        int cl = (int)(p >> 17);
        atomicAdd(&cnt[cl], 1);
        if (!ones) atomicAdd(&wsum[cl], wbuf[i]);
    }
    __syncthreads();
    int v = cnt[t];
    pre[t] = v;
    __syncthreads();
    for (int off = 1; off < 512; off <<= 1) {
        int add = (t >= off) ? pre[t - off] : 0;
        __syncthreads();
        pre[t] += add;
        __syncthreads();
    }
    int node = b * NPB + t;
    if (node < N) {
        row_ptr[node] = bs + pre[t] - v;
        float d = ones ? (float)v : wsum[t];
        dinv[node] = (d > 0.f) ? rsqrtf(fmaxf(d, 1e-12f)) : 0.f;
    }
}

// K6: per-bucket placement + norm -> csr_pack (int2: src, norm). Writes land in
// the bucket's contiguous CSR region (single-block local -> merged in L2).
__global__ __launch_bounds__(512) void kcsr_b_kernel(const unsigned int* ebuf,
                                                     const float* wbuf, const int* flags,
                                                     const int* bstart, const int* btot,
                                                     const int* row_ptr, const float* dinv,
                                                     int2* csr_pack, int N) {
    __shared__ int cur[512];
    __shared__ float dloc[512];
    int b = blockIdx.x;
    int t = threadIdx.x;
    int ones = flags[3];
    int node = b * NPB + t;
    cur[t] = (node < N) ? row_ptr[node] : 0;
    dloc[t] = (node < N) ? dinv[node] : 0.f;
    __syncthreads();
    int bs = bstart[b];
    int be = bs + btot[b];
    for (int i = bs + t; i < be; i += 512) {
        unsigned int p = ebuf[i];
        int cl = (int)(p >> 17);
        int r = (int)(p & 0x1FFFFu);
        float w = ones ? 1.0f : wbuf[i];
        float nv = dinv[r] * w * dloc[cl];
        int pos = atomicAdd(&cur[cl], 1);      // LDS atomic holding global pos
        csr_pack[pos] = make_int2(r, __float_as_int(nv));
    }
}

// ---------------------------------------------------------------------------
// In-register fp32 -> (bf16 hi, bf16 lo) split: v ~= hi + lo to ~2^-17 rel.
// ---------------------------------------------------------------------------
__device__ inline void split8v(f32x8 v, bf16x8& hi, bf16x8& lo) {
    for (int i = 0; i < 8; i++) {
        float f = v[i];
        unsigned short h = f2bf(f);
        hi[i] = (short)h;
        lo[i] = (short)f2bf(f - bf2f(h));
    }
}

// ---------------------------------------------------------------------------
// GEMM layer 1: C[M,64](bf16) = A[M,K] * W[64,K]^T.
// Block = 64 rows (4 waves x 16-row tile); wave computes 16x64 via 4 col-frags.
// Each A element is loaded+split exactly once; W comes pre-split (Whi/Wlo).
// Frag layouts per guide §3 (m89/m91): A[m=lane&15][k=quad*8+j]; B=W[n][k];
// D: col=lane&15, row=quad*4+reg.
// ---------------------------------------------------------------------------
__global__ __launch_bounds__(256) void gemm1_kernel(const void* A,
                             const unsigned short* Whi, const unsigned short* Wlo,
                             const int* flags, unsigned short* C, int M, int K) {
    int wave = threadIdx.x >> 6;
    int l = threadIdx.x & 63;
    int m = l & 15;
    int quad = l >> 4;
    int row0 = blockIdx.x * 64 + wave * 16;
    bool arow_ok = (row0 + m) < M;
    int fb = flags[2];
    f32x4 acc[4];
    #pragma unroll
    for (int n = 0; n < 4; n++) acc[n] = (f32x4){0.f, 0.f, 0.f, 0.f};
    bf16x8 zf = {0, 0, 0, 0, 0, 0, 0, 0};
    long long abase = (long long)(row0 + m) * K + quad * 8;
    if (fb) {
        const short* As = (const short*)A;
        #pragma unroll 4
        for (int k0 = 0; k0 < K; k0 += 32) {
            bf16x8 a = arow_ok ? *(const bf16x8*)(As + abase + k0) : zf;
            #pragma unroll
            for (int n = 0; n < 4; n++) {
                const unsigned short* wp = Whi + (long long)(n * 16 + m) * K + k0 + quad * 8;
                bf16x8 b = *(const bf16x8*)wp;
                acc[n] = __builtin_amdgcn_mfma_f32_16x16x32_bf16(a, b, acc[n], 0, 0, 0);
            }
        }
    } else {
        const float* Af = (const float*)A;
        #pragma unroll 2
        for (int k0 = 0; k0 < K; k0 += 32) {
            bf16x8 ah = zf, al = zf;
            if (arow_ok) {
                f32x8 av = *(const f32x8*)(Af + abase + k0);
                split8v(av, ah, al);
            }
            #pragma unroll
            for (int n = 0; n < 4; n++) {
                long long widx = (long long)(n * 16 + m) * K + k0 + quad * 8;
                bf16x8 wh = *(const bf16x8*)(Whi + widx);
                bf16x8 wl = *(const bf16x8*)(Wlo + widx);
                acc[n] = __builtin_amdgcn_mfma_f32_16x16x32_bf16(ah, wh, acc[n], 0, 0, 0);
                acc[n] = __builtin_amdgcn_mfma_f32_16x16x32_bf16(al, wh, acc[n], 0, 0, 0);
                acc[n] = __builtin_amdgcn_mfma_f32_16x16x32_bf16(ah, wl, acc[n], 0, 0, 0);
            }
        }
    }
    #pragma unroll
    for (int n = 0; n < 4; n++) {
        #pragma unroll
        for (int r = 0; r < 4; r++) {
            int row = row0 + quad * 4 + r;
            if (row < M) C[(long long)row * 64 + n * 16 + m] = f2bf(acc[n][r]);
        }
    }
}

// GEMM 2: A is bf16 [M,64] (internal buffer); W pre-split. fb: 1 MFMA, else 2.
__global__ __launch_bounds__(256) void gemm2_kernel(const unsigned short* A,
                             const unsigned short* Whi, const unsigned short* Wlo,
                             const int* flags, unsigned short* C, int M) {
    int wave = threadIdx.x >> 6;
    int l = threadIdx.x & 63;
    int m = l & 15;
    int quad = l >> 4;
    int row0 = blockIdx.x * 64 + wave * 16;
    bool arow_ok = (row0 + m) < M;
    int fb = flags[2];
    f32x4 acc[4];
    #pragma unroll
    for (int n = 0; n < 4; n++) acc[n] = (f32x4){0.f, 0.f, 0.f, 0.f};
    bf16x8 zf = {0, 0, 0, 0, 0, 0, 0, 0};
    const short* As = (const short*)A;
    long long abase = (long long)(row0 + m) * 64 + quad * 8;
    #pragma unroll
    for (int k0 = 0; k0 < 64; k0 += 32) {
        bf16x8 a = arow_ok ? *(const bf16x8*)(As + abase + k0) : zf;
        #pragma unroll
        for (int n = 0; n < 4; n++) {
            long long widx = (long long)(n * 16 + m) * 64 + k0 + quad * 8;
            bf16x8 wh = *(const bf16x8*)(Whi + widx);
            acc[n] = __builtin_amdgcn_mfma_f32_16x16x32_bf16(a, wh, acc[n], 0, 0, 0);
            if (!fb) {
                bf16x8 wl = *(const bf16x8*)(Wlo + widx);
                acc[n] = __builtin_amdgcn_mfma_f32_16x16x32_bf16(a, wl, acc[n], 0, 0, 0);
            }
        }
    }
    #pragma unroll
    for (int n = 0; n < 4; n++) {
        #pragma unroll
        for (int r = 0; r < 4; r++) {
            int row = row0 + quad * 4 + r;
            if (row < M) C[(long long)row * 64 + n * 16 + m] = f2bf(acc[n][r]);
        }
    }
}

// GEMM 3: [M,64] x W3[10,64]^T -> [M,16] bf16, zero-padded (W3 rows 10..15 = 0).
// Padded output lets the aggregation use full-wave 8B vector gathers.
__global__ __launch_bounds__(256) void gemm3_kernel(const unsigned short* A,
                             const unsigned short* Whi, const unsigned short* Wlo,
                             const int* flags, unsigned short* C, int M) {
    int wave = threadIdx.x >> 6;
    int l = threadIdx.x & 63;
    int m = l & 15;
    int quad = l >> 4;
    int row0 = blockIdx.x * 64 + wave * 16;
    bool arow_ok = (row0 + m) < M;
    int fb = flags[2];
    f32x4 acc = {0.f, 0.f, 0.f, 0.f};
    bf16x8 zf = {0, 0, 0, 0, 0, 0, 0, 0};
    const short* As = (const short*)A;
    long long abase = (long long)(row0 + m) * 64 + quad * 8;
    #pragma unroll
    for (int k0 = 0; k0 < 64; k0 += 32) {
        bf16x8 a = arow_ok ? *(const bf16x8*)(As + abase + k0) : zf;
        long long widx = (long long)m * 64 + k0 + quad * 8;
        bf16x8 wh = *(const bf16x8*)(Whi + widx);
        acc = __builtin_amdgcn_mfma_f32_16x16x32_bf16(a, wh, acc, 0, 0, 0);
        if (!fb) {
            bf16x8 wl = *(const bf16x8*)(Wlo + widx);
            acc = __builtin_amdgcn_mfma_f32_16x16x32_bf16(a, wl, acc, 0, 0, 0);
        }
    }
    #pragma unroll
    for (int r = 0; r < 4; r++) {
        int row = row0 + quad * 4 + r;
        if (row < M) C[(long long)row * 16 + m] = f2bf(acc[r]);
    }
}

// ---------------------------------------------------------------------------
// agg64s: feature-SLICED aggregation. blockIdx.y = slice s (0..3) selects 16
// features (32B of the 128B row). Per-slice gather table = N*32B = 3.2MB ->
// L2-resident per XCD (vs 12.8MB full table at ~31% hit). Dispatch is y-outer,
// so the device processes one slice at a time (cache phase coherence; order
// affects locality only, not correctness). Wave: g=l>>1 edge slot (32 in
// flight), j=l&1 16B half. Each wave handles 4 consecutive nodes.
// ---------------------------------------------------------------------------
__global__ __launch_bounds__(256) void agg64s_kernel(const unsigned short* h,
                              const void* bias, const int* flags, const int* row_ptr,
                              const int2* cp, unsigned short* outp, int n, int do_relu) {
    int l = threadIdx.x & 63;
    int wave = (int)(threadIdx.x >> 6);
    int s = (int)blockIdx.y;           // feature slice 0..3
    int g = l >> 1;                    // edge slot 0..31
    int j = l & 1;                     // 16B half of the 32B slice
    int f0 = s * 16 + j * 8;           // first feature this lane handles
    int nbase = ((int)blockIdx.x * 4 + wave) * 4;
    for (int nd = 0; nd < 4; nd++) {
        int node = nbase + nd;
        if (node >= n) break;          // wave-uniform
        int beg = row_ptr[node];
        int end = row_ptr[node + 1];
        float a0 = 0.f, a1 = 0.f, a2 = 0.f, a3 = 0.f;
        float a4 = 0.f, a5 = 0.f, a6 = 0.f, a7 = 0.f;
        for (int e = beg; e < end; e += 32) {
            int ee = e + g;
            if (ee < end) {
                int2 p = cp[ee];
                float nv = __int_as_float(p.y);
                uint4 raw = *(const uint4*)(h + (long long)p.x * 64 + f0);
                a0 += nv * __uint_as_float(raw.x << 16);
                a1 += nv * __uint_as_float(raw.x & 0xFFFF0000u);
                a2 += nv * __uint_as_float(raw.y << 16);
                a3 += nv * __uint_as_float(raw.y & 0xFFFF0000u);
                a4 += nv * __uint_as_float(raw.z << 16);
                a5 += nv * __uint_as_float(raw.z & 0xFFFF0000u);
                a6 += nv * __uint_as_float(raw.w << 16);
                a7 += nv * __uint_as_float(raw.w & 0xFFFF0000u);
            }
        }
        #pragma unroll
        for (int mask = 2; mask <= 32; mask <<= 1) {
            a0 += __shfl_xor(a0, mask);
            a1 += __shfl_xor(a1, mask);
            a2 += __shfl_xor(a2, mask);
            a3 += __shfl_xor(a3, mask);
            a4 += __shfl_xor(a4, mask);
            a5 += __shfl_xor(a5, mask);
            a6 += __shfl_xor(a6, mask);
            a7 += __shfl_xor(a7, mask);
        }
        if (g == 0) {
            int fb = flags[2];
            float v0 = a0 + feat(bias, f0 + 0, fb);
            float v1 = a1 + feat(bias, f0 + 1, fb);
            float v2 = a2 + feat(bias, f0 + 2, fb);
            float v3 = a3 + feat(bias, f0 + 3, fb);
            float v4 = a4 + feat(bias, f0 + 4, fb);
            float v5 = a5 + feat(bias, f0 + 5, fb);
            float v6 = a6 + feat(bias, f0 + 6, fb);
            float v7 = a7 + feat(bias, f0 + 7, fb);
            if (do_relu) {
                v0 = fmaxf(v0, 0.f); v1 = fmaxf(v1, 0.f);
                v2 = fmaxf(v2, 0.f); v3 = fmaxf(v3, 0.f);
                v4 = fmaxf(v4, 0.f); v5 = fmaxf(v5, 0.f);
                v6 = fmaxf(v6, 0.f); v7 = fmaxf(v7, 0.f);
            }
            uint4 pk;
            pk.x = (unsigned int)f2bf(v0) | ((unsigned int)f2bf(v1) << 16);
            pk.y = (unsigned int)f2bf(v2) | ((unsigned int)f2bf(v3) << 16);
            pk.z = (unsigned int)f2bf(v4) | ((unsigned int)f2bf(v5) << 16);
            pk.w = (unsigned int)f2bf(v6) | ((unsigned int)f2bf(v7) << 16);
            *(uint4*)(outp + (long long)node * 64 + f0) = pk;
        }
    }
}

// ---------------------------------------------------------------------------
// agg16: final aggregation over padded [N,16] bf16 h3 (only cols 0..9 nonzero).
// Wave per node; lane (g=l>>2: 16 edge slots, j=l&3: uint2 = 4 bf16 = 8B).
// Table (3.2MB) already L2-resident; simple loop (reverted MLP-unroll).
// ---------------------------------------------------------------------------
__global__ void agg16_kernel(const unsigned short* h, const void* bias,
                             const int* flags, const int* row_ptr,
                             const int2* cp, void* outp, int n) {
    int l = threadIdx.x & 63;
    int node = blockIdx.x * 4 + (int)(threadIdx.x >> 6);
    if (node >= n) return;
    int g = l >> 2;          // edge slot 0..15
    int j = l & 3;           // feature quad
    int beg = row_ptr[node];
    int end = row_ptr[node + 1];
    float a0 = 0.f, a1 = 0.f, a2 = 0.f, a3 = 0.f;
    for (int e = beg; e < end; e += 16) {
        int ee = e + g;
        if (ee < end) {
            int2 p = cp[ee];
            float nv = __int_as_float(p.y);
            uint2 raw = *(const uint2*)(h + (long long)p.x * 16 + j * 4);
            a0 += nv * __uint_as_float(raw.x << 16);
            a1 += nv * __uint_as_float(raw.x & 0xFFFF0000u);
            a2 += nv * __uint_as_float(raw.y << 16);
            a3 += nv * __uint_as_float(raw.y & 0xFFFF0000u);
        }
    }
    for (int mask = 4; mask <= 32; mask <<= 1) {
        a0 += __shfl_xor(a0, mask);
        a1 += __shfl_xor(a1, mask);
        a2 += __shfl_xor(a2, mask);
        a3 += __shfl_xor(a3, mask);
    }
    if (g == 0) {
        int fb = flags[2];
        float v[4] = {a0, a1, a2, a3};
        #pragma unroll
        for (int i = 0; i < 4; i++) {
            int f = j * 4 + i;
            if (f < 10) {
                float o = v[i] + feat(bias, f, fb);
                if (fb) ((unsigned short*)outp)[(long long)node * 10 + f] = f2bf(o);
                else    ((float*)outp)[(long long)node * 10 + f] = o;
            }
        }
    }
}

// ---------------------------------------------------------------------------
extern "C" void kernel_launch(void* const* d_in, const int* in_sizes, int n_in,
                              void* d_out, int out_size, void* d_ws, size_t ws_size,
                              hipStream_t stream) {
    const void* x  = d_in[0];
    const int*  ei = (const int*)d_in[1];
    const void* ew = d_in[2];
    const void* W1 = d_in[3];
    const void* b1 = d_in[4];
    const void* W2 = d_in[5];
    const void* b2 = d_in[6];
    const void* W3 = d_in[7];
    const void* b3 = d_in[8];

    const int N = in_sizes[0] / 256;   // 100000
    const int E = in_sizes[1] / 2;     // 3200000
    const int TB = 256;
    const int NB = (N + NPB - 1) / NPB;            // 196 buckets
    const int chunk = (E + PB - 1) / PB;           // 6250 edges/block

    size_t off = 0;
    size_t o_flags = off; off += 16;
    size_t o_ghist = off; off += (size_t)PB * NB * 4; off = (off + 15) & ~(size_t)15;
    size_t o_btot  = off; off += (size_t)NB * 4;
    size_t o_bst   = off; off += (size_t)NB * 4; off = (off + 15) & ~(size_t)15;
    size_t o_rp    = off; off += (size_t)(N + 1) * 4;
    size_t o_dinv  = off; off += (size_t)N * 4; off = (off + 15) & ~(size_t)15;
    size_t o_pack  = off; off += (size_t)E * 8;
    size_t o_bufA  = off; off += (size_t)N * 64 * 2;   // overlays wbuf (E*4)
    size_t o_bufB  = off; off += (size_t)N * 64 * 2;   // overlays ebuf (E*4)
    size_t o_h3    = off; off += (size_t)N * 16 * 2; off = (off + 15) & ~(size_t)15;
    size_t o_w1hi  = off; off += (size_t)64 * 256 * 2;
    size_t o_w1lo  = off; off += (size_t)64 * 256 * 2;
    size_t o_w2hi  = off; off += (size_t)64 * 64 * 2;
    size_t o_w2lo  = off; off += (size_t)64 * 64 * 2;
    size_t o_w3hi  = off; off += (size_t)16 * 64 * 2;
    size_t o_w3lo  = off; off += (size_t)16 * 64 * 2;
    size_t need = off;
    // overlay safety: E*4 must fit in N*64*2
    if (ws_size < need || (size_t)E * 4 > (size_t)N * 64 * 2) {
        sentinel_kernel<<<dim3((out_size + TB - 1) / TB), dim3(TB), 0, stream>>>(
            (unsigned short*)d_out, out_size, 250.0f);
        return;
    }
    char* ws = (char*)d_ws;
    int*   flags    = (int*)(ws + o_flags);
    int*   ghist    = (int*)(ws + o_ghist);
    int*   btot     = (int*)(ws + o_btot);
    int*   bstart   = (int*)(ws + o_bst);
    int*   row_ptr  = (int*)(ws + o_rp);
    float* dinv     = (float*)(ws + o_dinv);
    int2*  csr_pack = (int2*)(ws + o_pack);
    unsigned short* bufA  = (unsigned short*)(ws + o_bufA);
    unsigned short* bufB  = (unsigned short*)(ws + o_bufB);
    unsigned short* h3buf = (unsigned short*)(ws + o_h3);
    unsigned short* w1hi  = (unsigned short*)(ws + o_w1hi);
    unsigned short* w1lo  = (unsigned short*)(ws + o_w1lo);
    unsigned short* w2hi  = (unsigned short*)(ws + o_w2hi);
    unsigned short* w2lo  = (unsigned short*)(ws + o_w2lo);
    unsigned short* w3hi  = (unsigned short*)(ws + o_w3hi);
    unsigned short* w3lo  = (unsigned short*)(ws + o_w3lo);
    float*        wbuf = (float*)bufA;         // lifetime ends before gemm1
    unsigned int* ebuf = (unsigned int*)bufB;  // lifetime ends before agg64 #1

    dim3 tb(TB);
    dim3 tb512(512);
    dim3 gE4((E / 4 + TB - 1) / TB);
    dim3 gG((N + 63) / 64);
    dim3 gAgg((N + 3) / 4);
    dim3 gAggS((N + 15) / 16, 4);      // 4 nodes/wave x 4 waves; y = feature slice
    dim3 one(1);

    // --- detect formats; one-time weight splits; bucketed CSR build ---
    detect_kernel<<<one, tb, 0, stream>>>(ei, (const unsigned short*)ew,
                                          (const unsigned short*)x, flags);
    wsplit_kernel<<<dim3(64), tb, 0, stream>>>(W1, flags, w1hi, w1lo,
                                               64 * 256, 64 * 256);
    wsplit_kernel<<<dim3(16), tb, 0, stream>>>(W2, flags, w2hi, w2lo,
                                               64 * 64, 64 * 64);
    wsplit_kernel<<<dim3(4), tb, 0, stream>>>(W3, flags, w3hi, w3lo,
                                              10 * 64, 16 * 64);
    ones_kernel<<<gE4, tb, 0, stream>>>(ew, flags, E);
    khist_kernel<<<dim3(PB), tb512, 0, stream>>>(ei, flags, ghist, E, N, NB, chunk);
    koff1_kernel<<<dim3(NB), tb512, 0, stream>>>(ghist, btot, NB);
    koff2_kernel<<<one, tb, 0, stream>>>(btot, bstart, row_ptr, NB, N, E);
    kscatter_kernel<<<dim3(PB), tb512, 0, stream>>>(ei, ew, flags, ghist, bstart,
                                                    ebuf, wbuf, E, N, NB, chunk);
    kcsr_a_kernel<<<dim3(NB), tb512, 0, stream>>>(ebuf, wbuf, flags, bstart, btot,
                                                  row_ptr, dinv, N);
    kcsr_b_kernel<<<dim3(NB), tb512, 0, stream>>>(ebuf, wbuf, flags, bstart, btot,
                                                  row_ptr, dinv, csr_pack, N);

    // --- Layer 1: h1 = X*W1^T ; a1 = relu(S h1 + b1) ---
    gemm1_kernel<<<gG, tb, 0, stream>>>(x, w1hi, w1lo, flags, bufA, N, 256);
    agg64s_kernel<<<gAggS, tb, 0, stream>>>(bufA, b1, flags, row_ptr, csr_pack,
                                            bufB, N, 1);
    // --- Layer 2 ---
    gemm2_kernel<<<gG, tb, 0, stream>>>(bufB, w2hi, w2lo, flags, bufA, N);
    agg64s_kernel<<<gAggS, tb, 0, stream>>>(bufA, b2, flags, row_ptr, csr_pack,
                                            bufB, N, 1);
    // --- Layer 3 ---
    gemm3_kernel<<<gG, tb, 0, stream>>>(bufB, w3hi, w3lo, flags, h3buf, N);
    agg16_kernel<<<gAgg, tb, 0, stream>>>(h3buf, b3, flags, row_ptr, csr_pack,
                                          d_out, N);
}

// Round 9
// 740.058 us; speedup vs baseline: 1.1304x; 1.1304x over previous
//
#include <hip/hip_runtime.h>
#include <stddef.h>

typedef __attribute__((ext_vector_type(8))) short bf16x8;   // MFMA A/B frag
typedef __attribute__((ext_vector_type(4))) float f32x4;    // MFMA C/D frag
typedef __attribute__((ext_vector_type(8))) float f32x8;    // 32B fp32 load

#define NPB 512            // nodes per bucket (power of 2: bucket = c >> 9)
#define PB  512            // scatter blocks

// ---------------------------------------------------------------------------
// Manual bf16 <-> fp32 (storage type = unsigned short)
// ---------------------------------------------------------------------------
__device__ inline float bf2f(unsigned short u) {
    unsigned int v = ((unsigned int)u) << 16;
    float f;
    __builtin_memcpy(&f, &v, 4);
    return f;
}
__device__ inline unsigned short f2bf(float f) {
    unsigned int v;
    __builtin_memcpy(&v, &f, 4);
    unsigned int r = (v + 0x7FFFu + ((v >> 16) & 1u)) >> 16;   // RNE
    return (unsigned short)r;
}
__device__ inline float feat(const void* p, long long idx, int isbf) {
    if (isbf) return bf2f(((const unsigned short*)p)[idx]);
    return ((const float*)p)[idx];
}
__device__ inline int clampi(int v, int lo, int hi) {
    return v < lo ? lo : (v > hi ? hi : v);
}

// ---------------------------------------------------------------------------
// Format detection. flags[0]=edge_index int64; flags[1]=edge_weight bf16;
// flags[2]=features bf16; flags[3]=all edge_weights == 1.0.
// ---------------------------------------------------------------------------
__global__ void detect_kernel(const int* ei, const unsigned short* ew16,
                              const unsigned short* x16, int* flags) {
    __shared__ int s_is64, s_pass;
    if (threadIdx.x == 0) { s_is64 = 1; s_pass = 0; }
    __syncthreads();
    int t = threadIdx.x;
    if (t < 128 && ei[2 * t + 1] != 0) atomicAnd(&s_is64, 0);
    if (t < 64) {
        unsigned short h = x16[t];
        unsigned int expf = (h >> 7) & 0xFF;
        if (h == 0 || (expf >= 112 && expf <= 142)) atomicAdd(&s_pass, 1);
    }
    __syncthreads();
    if (t == 0) {
        flags[0] = s_is64;
        flags[1] = (ew16[0] == 0x3F80) ? 1 : 0;
        flags[2] = (s_pass >= 56) ? 1 : 0;
        flags[3] = 1;
    }
}

__global__ void ones_kernel(const void* ew, int* flags, int E) {
    int i = blockIdx.x * blockDim.x + threadIdx.x;
    int wbf = flags[1];
    int b = i * 4;
    int lim = b + 4 < E ? b + 4 : E;
    bool bad = false;
    for (int k = b; k < lim; k++)
        if (feat(ew, k, wbf) != 1.0f) bad = true;
    if (bad) atomicAnd(&flags[3], 0);
}

__global__ void sentinel_kernel(unsigned short* outp, int n, float val) {
    int i = blockIdx.x * blockDim.x + threadIdx.x;
    if (i < n) outp[i] = f2bf(val);
}

// ---------------------------------------------------------------------------
// One-time weight split: W (fp32 or bf16) -> (Whi, Wlo) bf16 pair.
// fp32: v ~= hi + lo; bf16 input: hi = v, lo = 0. Zero-pads to n_out.
// ---------------------------------------------------------------------------
__global__ void wsplit_kernel(const void* W, const int* flags, unsigned short* hi,
                              unsigned short* lo, int n_in, int n_out) {
    int i = blockIdx.x * blockDim.x + threadIdx.x;
    if (i >= n_out) return;
    if (i >= n_in) { hi[i] = 0; lo[i] = 0; return; }
    if (flags[2]) {
        hi[i] = ((const unsigned short*)W)[i];
        lo[i] = 0;
    } else {
        float v = ((const float*)W)[i];
        unsigned short h = f2bf(v);
        hi[i] = h;
        lo[i] = f2bf(v - bf2f(h));
    }
}

// ---------------------------------------------------------------------------
// Bucketed CSR build (atomic-light; all heavy writes locality-grouped)
// ---------------------------------------------------------------------------
// K1: per-block bucket histograms (LDS atomics only)
__global__ __launch_bounds__(512) void khist_kernel(const int* ei, const int* flags,
                                                    int* ghist, int E, int n,
                                                    int NB, int chunk) {
    __shared__ int hist[256];
    int blk = blockIdx.x;
    for (int i = threadIdx.x; i < NB; i += blockDim.x) hist[i] = 0;
    __syncthreads();
    int is64 = flags[0];
    int e0 = blk * chunk;
    int e1 = e0 + chunk < E ? e0 + chunk : E;
    for (int e = e0 + (int)threadIdx.x; e < e1; e += blockDim.x) {
        int c = is64 ? ei[2 * (E + e)] : ei[E + e];
        c = clampi(c, 0, n - 1);
        atomicAdd(&hist[c >> 9], 1);
    }
    __syncthreads();
    for (int i = threadIdx.x; i < NB; i += blockDim.x) ghist[blk * NB + i] = hist[i];
}

// K2: per-bucket exclusive scan over the PB block histograms (in place) + totals
__global__ __launch_bounds__(512) void koff1_kernel(int* ghist, int* btot, int NB) {
    __shared__ int s[512];
    int b = blockIdx.x;
    int t = threadIdx.x;
    int v = ghist[t * NB + b];
    s[t] = v;
    __syncthreads();
    for (int off = 1; off < 512; off <<= 1) {
        int add = (t >= off) ? s[t - off] : 0;
        __syncthreads();
        s[t] += add;
        __syncthreads();
    }
    ghist[t * NB + b] = s[t] - v;              // exclusive
    if (t == 511) btot[b] = s[511];
}

// K3: scan bucket totals -> bstart; write row_ptr[N] = E
__global__ __launch_bounds__(256) void koff2_kernel(const int* btot, int* bstart,
                                                    int* row_ptr, int NB, int N, int E) {
    __shared__ int s[256];
    int t = threadIdx.x;
    int v = (t < NB) ? btot[t] : 0;
    s[t] = v;
    __syncthreads();
    for (int off = 1; off < 256; off <<= 1) {
        int add = (t >= off) ? s[t - off] : 0;
        __syncthreads();
        s[t] += add;
        __syncthreads();
    }
    if (t < NB) bstart[t] = s[t] - v;
    if (t == 0) row_ptr[N] = E;
}

// K4: scatter edges into bucket-grouped ebuf (pack: c_local<<17 | r), deterministic
// offsets (no global atomics). wbuf written only on the general-weight path.
__global__ __launch_bounds__(512) void kscatter_kernel(const int* ei, const void* ew,
                                                       const int* flags, const int* ghist,
                                                       const int* bstart,
                                                       unsigned int* ebuf, float* wbuf,
                                                       int E, int n, int NB, int chunk) {
    __shared__ int cur[256];
    int blk = blockIdx.x;
    for (int i = threadIdx.x; i < NB; i += blockDim.x)
        cur[i] = ghist[blk * NB + i] + bstart[i];
    __syncthreads();
    int is64 = flags[0], wbf = flags[1], ones = flags[3];
    int e0 = blk * chunk;
    int e1 = e0 + chunk < E ? e0 + chunk : E;
    for (int e = e0 + (int)threadIdx.x; e < e1; e += blockDim.x) {
        int r = is64 ? ei[2 * e] : ei[e];
        int c = is64 ? ei[2 * (E + e)] : ei[E + e];
        r = clampi(r, 0, n - 1);
        c = clampi(c, 0, n - 1);
        int b = c >> 9;
        int pos = atomicAdd(&cur[b], 1);       // LDS atomic
        ebuf[pos] = ((unsigned int)(c & 511) << 17) | (unsigned int)r;
        if (!ones) wbuf[pos] = feat(ew, e, wbf);
    }
}

// K5: per-bucket node counts -> row_ptr + dinv (no global atomics)
__global__ __launch_bounds__(512) void kcsr_a_kernel(const unsigned int* ebuf,
                                                     const float* wbuf, const int* flags,
                                                     const int* bstart, const int* btot,
                                                     int* row_ptr, float* dinv, int N) {
    __shared__ int cnt[512];
    __shared__ int pre[512];
    __shared__ float wsum[512];
    int b = blockIdx.x;
    int t = threadIdx.x;
    int ones = flags[3];
    cnt[t] = 0;
    wsum[t] = 0.f;
    __syncthreads();
    int bs = bstart[b];
    int be = bs + btot[b];
    for (int i = bs + t; i < be; i += 512) {
        unsigned int p = ebuf[i];
        int cl = (int)(p >> 17);
        atomicAdd(&cnt[cl], 1);
        if (!ones) atomicAdd(&wsum[cl], wbuf[i]);
    }
    __syncthreads();
    int v = cnt[t];
    pre[t] = v;
    __syncthreads();
    for (int off = 1; off < 512; off <<= 1) {
        int add = (t >= off) ? pre[t - off] : 0;
        __syncthreads();
        pre[t] += add;
        __syncthreads();
    }
    int node = b * NPB + t;
    if (node < N) {
        row_ptr[node] = bs + pre[t] - v;
        float d = ones ? (float)v : wsum[t];
        dinv[node] = (d > 0.f) ? rsqrtf(fmaxf(d, 1e-12f)) : 0.f;
    }
}

// K6: per-bucket placement + norm -> csr_pack (int2: src, norm). Writes land in
// the bucket's contiguous CSR region (single-block local -> merged in L2).
__global__ __launch_bounds__(512) void kcsr_b_kernel(const unsigned int* ebuf,
                                                     const float* wbuf, const int* flags,
                                                     const int* bstart, const int* btot,
                                                     const int* row_ptr, const float* dinv,
                                                     int2* csr_pack, int N) {
    __shared__ int cur[512];
    __shared__ float dloc[512];
    int b = blockIdx.x;
    int t = threadIdx.x;
    int ones = flags[3];
    int node = b * NPB + t;
    cur[t] = (node < N) ? row_ptr[node] : 0;
    dloc[t] = (node < N) ? dinv[node] : 0.f;
    __syncthreads();
    int bs = bstart[b];
    int be = bs + btot[b];
    for (int i = bs + t; i < be; i += 512) {
        unsigned int p = ebuf[i];
        int cl = (int)(p >> 17);
        int r = (int)(p & 0x1FFFFu);
        float w = ones ? 1.0f : wbuf[i];
        float nv = dinv[r] * w * dloc[cl];
        int pos = atomicAdd(&cur[cl], 1);      // LDS atomic holding global pos
        csr_pack[pos] = make_int2(r, __float_as_int(nv));
    }
}

// ---------------------------------------------------------------------------
// In-register fp32 -> (bf16 hi, bf16 lo) split: v ~= hi + lo to ~2^-17 rel.
// ---------------------------------------------------------------------------
__device__ inline void split8v(f32x8 v, bf16x8& hi, bf16x8& lo) {
    for (int i = 0; i < 8; i++) {
        float f = v[i];
        unsigned short h = f2bf(f);
        hi[i] = (short)h;
        lo[i] = (short)f2bf(f - bf2f(h));
    }
}

// ---------------------------------------------------------------------------
// GEMM layer 1: Cs[slice][M][16](bf16) = A[M,K] * W[64,K]^T, SLICE-MAJOR out.
// Slice = col-frag n (cols n*16..n*16+15), each slice table = M*32B contiguous
// -> the aggregation's per-slice gather footprint is truly L2-resident.
// Block = 64 rows (4 waves x 16-row tile); wave computes 16x64 via 4 col-frags.
// ---------------------------------------------------------------------------
__global__ __launch_bounds__(256) void gemm1_kernel(const void* A,
                             const unsigned short* Whi, const unsigned short* Wlo,
                             const int* flags, unsigned short* C, int M, int K) {
    int wave = threadIdx.x >> 6;
    int l = threadIdx.x & 63;
    int m = l & 15;
    int quad = l >> 4;
    int row0 = blockIdx.x * 64 + wave * 16;
    bool arow_ok = (row0 + m) < M;
    int fb = flags[2];
    f32x4 acc[4];
    #pragma unroll
    for (int n = 0; n < 4; n++) acc[n] = (f32x4){0.f, 0.f, 0.f, 0.f};
    bf16x8 zf = {0, 0, 0, 0, 0, 0, 0, 0};
    long long abase = (long long)(row0 + m) * K + quad * 8;
    if (fb) {
        const short* As = (const short*)A;
        #pragma unroll 4
        for (int k0 = 0; k0 < K; k0 += 32) {
            bf16x8 a = arow_ok ? *(const bf16x8*)(As + abase + k0) : zf;
            #pragma unroll
            for (int n = 0; n < 4; n++) {
                const unsigned short* wp = Whi + (long long)(n * 16 + m) * K + k0 + quad * 8;
                bf16x8 b = *(const bf16x8*)wp;
                acc[n] = __builtin_amdgcn_mfma_f32_16x16x32_bf16(a, b, acc[n], 0, 0, 0);
            }
        }
    } else {
        const float* Af = (const float*)A;
        #pragma unroll 2
        for (int k0 = 0; k0 < K; k0 += 32) {
            bf16x8 ah = zf, al = zf;
            if (arow_ok) {
                f32x8 av = *(const f32x8*)(Af + abase + k0);
                split8v(av, ah, al);
            }
            #pragma unroll
            for (int n = 0; n < 4; n++) {
                long long widx = (long long)(n * 16 + m) * K + k0 + quad * 8;
                bf16x8 wh = *(const bf16x8*)(Whi + widx);
                bf16x8 wl = *(const bf16x8*)(Wlo + widx);
                acc[n] = __builtin_amdgcn_mfma_f32_16x16x32_bf16(ah, wh, acc[n], 0, 0, 0);
                acc[n] = __builtin_amdgcn_mfma_f32_16x16x32_bf16(al, wh, acc[n], 0, 0, 0);
                acc[n] = __builtin_amdgcn_mfma_f32_16x16x32_bf16(ah, wl, acc[n], 0, 0, 0);
            }
        }
    }
    #pragma unroll
    for (int n = 0; n < 4; n++) {
        #pragma unroll
        for (int r = 0; r < 4; r++) {
            int row = row0 + quad * 4 + r;
            if (row < M) C[((long long)n * M + row) * 16 + m] = f2bf(acc[n][r]);
        }
    }
}

// GEMM 2: A is bf16 [M,64] row-major (agg output); SLICE-MAJOR output like gemm1.
__global__ __launch_bounds__(256) void gemm2_kernel(const unsigned short* A,
                             const unsigned short* Whi, const unsigned short* Wlo,
                             const int* flags, unsigned short* C, int M) {
    int wave = threadIdx.x >> 6;
    int l = threadIdx.x & 63;
    int m = l & 15;
    int quad = l >> 4;
    int row0 = blockIdx.x * 64 + wave * 16;
    bool arow_ok = (row0 + m) < M;
    int fb = flags[2];
    f32x4 acc[4];
    #pragma unroll
    for (int n = 0; n < 4; n++) acc[n] = (f32x4){0.f, 0.f, 0.f, 0.f};
    bf16x8 zf = {0, 0, 0, 0, 0, 0, 0, 0};
    const short* As = (const short*)A;
    long long abase = (long long)(row0 + m) * 64 + quad * 8;
    #pragma unroll
    for (int k0 = 0; k0 < 64; k0 += 32) {
        bf16x8 a = arow_ok ? *(const bf16x8*)(As + abase + k0) : zf;
        #pragma unroll
        for (int n = 0; n < 4; n++) {
            long long widx = (long long)(n * 16 + m) * 64 + k0 + quad * 8;
            bf16x8 wh = *(const bf16x8*)(Whi + widx);
            acc[n] = __builtin_amdgcn_mfma_f32_16x16x32_bf16(a, wh, acc[n], 0, 0, 0);
            if (!fb) {
                bf16x8 wl = *(const bf16x8*)(Wlo + widx);
                acc[n] = __builtin_amdgcn_mfma_f32_16x16x32_bf16(a, wl, acc[n], 0, 0, 0);
            }
        }
    }
    #pragma unroll
    for (int n = 0; n < 4; n++) {
        #pragma unroll
        for (int r = 0; r < 4; r++) {
            int row = row0 + quad * 4 + r;
            if (row < M) C[((long long)n * M + row) * 16 + m] = f2bf(acc[n][r]);
        }
    }
}

// GEMM 3: [M,64] x W3[10,64]^T -> [M,16] bf16, zero-padded (W3 rows 10..15 = 0).
// Input row-major (agg output); padded output = exactly one slice table.
__global__ __launch_bounds__(256) void gemm3_kernel(const unsigned short* A,
                             const unsigned short* Whi, const unsigned short* Wlo,
                             const int* flags, unsigned short* C, int M) {
    int wave = threadIdx.x >> 6;
    int l = threadIdx.x & 63;
    int m = l & 15;
    int quad = l >> 4;
    int row0 = blockIdx.x * 64 + wave * 16;
    bool arow_ok = (row0 + m) < M;
    int fb = flags[2];
    f32x4 acc = {0.f, 0.f, 0.f, 0.f};
    bf16x8 zf = {0, 0, 0, 0, 0, 0, 0, 0};
    const short* As = (const short*)A;
    long long abase = (long long)(row0 + m) * 64 + quad * 8;
    #pragma unroll
    for (int k0 = 0; k0 < 64; k0 += 32) {
        bf16x8 a = arow_ok ? *(const bf16x8*)(As + abase + k0) : zf;
        long long widx = (long long)m * 64 + k0 + quad * 8;
        bf16x8 wh = *(const bf16x8*)(Whi + widx);
        acc = __builtin_amdgcn_mfma_f32_16x16x32_bf16(a, wh, acc, 0, 0, 0);
        if (!fb) {
            bf16x8 wl = *(const bf16x8*)(Wlo + widx);
            acc = __builtin_amdgcn_mfma_f32_16x16x32_bf16(a, wl, acc, 0, 0, 0);
        }
    }
    #pragma unroll
    for (int r = 0; r < 4; r++) {
        int row = row0 + quad * 4 + r;
        if (row < M) C[(long long)row * 16 + m] = f2bf(acc[r]);
    }
}

// ---------------------------------------------------------------------------
// agg64s: feature-sliced aggregation over SLICE-MAJOR tables hs = h + s*N*16.
// Per-slice table = N*32B = 3.2MB contiguous -> L2-resident (compulsory-only
// misses). Wave per node; lane (g=l>>2: 16 edge slots, j=l&3: 8B quad) --
// the proven agg16 shape. Output row-major [node][64] for the next GEMM.
// blockIdx.y = slice; dispatch is y-outer so slices phase through the device.
// ---------------------------------------------------------------------------
__global__ void agg64s_kernel(const unsigned short* h, const void* bias,
                              const int* flags, const int* row_ptr,
                              const int2* cp, unsigned short* outp, int n, int do_relu) {
    int l = threadIdx.x & 63;
    int node = blockIdx.x * 4 + (int)(threadIdx.x >> 6);
    if (node >= n) return;
    int s = (int)blockIdx.y;
    const unsigned short* hs = h + (size_t)s * n * 16;
    int g = l >> 2;          // edge slot 0..15
    int j = l & 3;           // 8B feature quad within the 32B slice row
    int beg = row_ptr[node];
    int end = row_ptr[node + 1];
    float a0 = 0.f, a1 = 0.f, a2 = 0.f, a3 = 0.f;
    for (int e = beg; e < end; e += 16) {
        int ee = e + g;
        if (ee < end) {
            int2 p = cp[ee];
            float nv = __int_as_float(p.y);
            uint2 raw = *(const uint2*)(hs + (long long)p.x * 16 + j * 4);
            a0 += nv * __uint_as_float(raw.x << 16);
            a1 += nv * __uint_as_float(raw.x & 0xFFFF0000u);
            a2 += nv * __uint_as_float(raw.y << 16);
            a3 += nv * __uint_as_float(raw.y & 0xFFFF0000u);
        }
    }
    for (int mask = 4; mask <= 32; mask <<= 1) {
        a0 += __shfl_xor(a0, mask);
        a1 += __shfl_xor(a1, mask);
        a2 += __shfl_xor(a2, mask);
        a3 += __shfl_xor(a3, mask);
    }
    if (g == 0) {
        int fb = flags[2];
        int f0 = s * 16 + j * 4;
        float v0 = a0 + feat(bias, f0 + 0, fb);
        float v1 = a1 + feat(bias, f0 + 1, fb);
        float v2 = a2 + feat(bias, f0 + 2, fb);
        float v3 = a3 + feat(bias, f0 + 3, fb);
        if (do_relu) {
            v0 = fmaxf(v0, 0.f); v1 = fmaxf(v1, 0.f);
            v2 = fmaxf(v2, 0.f); v3 = fmaxf(v3, 0.f);
        }
        uint2 pk;
        pk.x = (unsigned int)f2bf(v0) | ((unsigned int)f2bf(v1) << 16);
        pk.y = (unsigned int)f2bf(v2) | ((unsigned int)f2bf(v3) << 16);
        *(uint2*)(outp + (long long)node * 64 + f0) = pk;
    }
}

// ---------------------------------------------------------------------------
// agg16: final aggregation over padded [N,16] bf16 h3 (only cols 0..9 nonzero).
// Wave per node; lane (g=l>>2: 16 edge slots, j=l&3: uint2 = 4 bf16 = 8B).
// Table (3.2MB) L2-resident.
// ---------------------------------------------------------------------------
__global__ void agg16_kernel(const unsigned short* h, const void* bias,
                             const int* flags, const int* row_ptr,
                             const int2* cp, void* outp, int n) {
    int l = threadIdx.x & 63;
    int node = blockIdx.x * 4 + (int)(threadIdx.x >> 6);
    if (node >= n) return;
    int g = l >> 2;          // edge slot 0..15
    int j = l & 3;           // feature quad
    int beg = row_ptr[node];
    int end = row_ptr[node + 1];
    float a0 = 0.f, a1 = 0.f, a2 = 0.f, a3 = 0.f;
    for (int e = beg; e < end; e += 16) {
        int ee = e + g;
        if (ee < end) {
            int2 p = cp[ee];
            float nv = __int_as_float(p.y);
            uint2 raw = *(const uint2*)(h + (long long)p.x * 16 + j * 4);
            a0 += nv * __uint_as_float(raw.x << 16);
            a1 += nv * __uint_as_float(raw.x & 0xFFFF0000u);
            a2 += nv * __uint_as_float(raw.y << 16);
            a3 += nv * __uint_as_float(raw.y & 0xFFFF0000u);
        }
    }
    for (int mask = 4; mask <= 32; mask <<= 1) {
        a0 += __shfl_xor(a0, mask);
        a1 += __shfl_xor(a1, mask);
        a2 += __shfl_xor(a2, mask);
        a3 += __shfl_xor(a3, mask);
    }
    if (g == 0) {
        int fb = flags[2];
        float v[4] = {a0, a1, a2, a3};
        #pragma unroll
        for (int i = 0; i < 4; i++) {
            int f = j * 4 + i;
            if (f < 10) {
                float o = v[i] + feat(bias, f, fb);
                if (fb) ((unsigned short*)outp)[(long long)node * 10 + f] = f2bf(o);
                else    ((float*)outp)[(long long)node * 10 + f] = o;
            }
        }
    }
}

// ---------------------------------------------------------------------------
extern "C" void kernel_launch(void* const* d_in, const int* in_sizes, int n_in,
                              void* d_out, int out_size, void* d_ws, size_t ws_size,
                              hipStream_t stream) {
    const void* x  = d_in[0];
    const int*  ei = (const int*)d_in[1];
    const void* ew = d_in[2];
    const void* W1 = d_in[3];
    const void* b1 = d_in[4];
    const void* W2 = d_in[5];
    const void* b2 = d_in[6];
    const void* W3 = d_in[7];
    const void* b3 = d_in[8];

    const int N = in_sizes[0] / 256;   // 100000
    const int E = in_sizes[1] / 2;     // 3200000
    const int TB = 256;
    const int NB = (N + NPB - 1) / NPB;            // 196 buckets
    const int chunk = (E + PB - 1) / PB;           // 6250 edges/block

    size_t off = 0;
    size_t o_flags = off; off += 16;
    size_t o_ghist = off; off += (size_t)PB * NB * 4; off = (off + 15) & ~(size_t)15;
    size_t o_btot  = off; off += (size_t)NB * 4;
    size_t o_bst   = off; off += (size_t)NB * 4; off = (off + 15) & ~(size_t)15;
    size_t o_rp    = off; off += (size_t)(N + 1) * 4;
    size_t o_dinv  = off; off += (size_t)N * 4; off = (off + 15) & ~(size_t)15;
    size_t o_pack  = off; off += (size_t)E * 8;
    size_t o_bufA  = off; off += (size_t)N * 64 * 2;   // overlays wbuf (E*4)
    size_t o_bufB  = off; off += (size_t)N * 64 * 2;   // overlays ebuf (E*4)
    size_t o_h3    = off; off += (size_t)N * 16 * 2; off = (off + 15) & ~(size_t)15;
    size_t o_w1hi  = off; off += (size_t)64 * 256 * 2;
    size_t o_w1lo  = off; off += (size_t)64 * 256 * 2;
    size_t o_w2hi  = off; off += (size_t)64 * 64 * 2;
    size_t o_w2lo  = off; off += (size_t)64 * 64 * 2;
    size_t o_w3hi  = off; off += (size_t)16 * 64 * 2;
    size_t o_w3lo  = off; off += (size_t)16 * 64 * 2;
    size_t need = off;
    // overlay safety: E*4 must fit in N*64*2
    if (ws_size < need || (size_t)E * 4 > (size_t)N * 64 * 2) {
        sentinel_kernel<<<dim3((out_size + TB - 1) / TB), dim3(TB), 0, stream>>>(
            (unsigned short*)d_out, out_size, 250.0f);
        return;
    }
    char* ws = (char*)d_ws;
    int*   flags    = (int*)(ws + o_flags);
    int*   ghist    = (int*)(ws + o_ghist);
    int*   btot     = (int*)(ws + o_btot);
    int*   bstart   = (int*)(ws + o_bst);
    int*   row_ptr  = (int*)(ws + o_rp);
    float* dinv     = (float*)(ws + o_dinv);
    int2*  csr_pack = (int2*)(ws + o_pack);
    unsigned short* bufA  = (unsigned short*)(ws + o_bufA);
    unsigned short* bufB  = (unsigned short*)(ws + o_bufB);
    unsigned short* h3buf = (unsigned short*)(ws + o_h3);
    unsigned short* w1hi  = (unsigned short*)(ws + o_w1hi);
    unsigned short* w1lo  = (unsigned short*)(ws + o_w1lo);
    unsigned short* w2hi  = (unsigned short*)(ws + o_w2hi);
    unsigned short* w2lo  = (unsigned short*)(ws + o_w2lo);
    unsigned short* w3hi  = (unsigned short*)(ws + o_w3hi);
    unsigned short* w3lo  = (unsigned short*)(ws + o_w3lo);
    float*        wbuf = (float*)bufA;         // lifetime ends before gemm1
    unsigned int* ebuf = (unsigned int*)bufB;  // lifetime ends before agg #1

    dim3 tb(TB);
    dim3 tb512(512);
    dim3 gE4((E / 4 + TB - 1) / TB);
    dim3 gG((N + 63) / 64);
    dim3 gAgg((N + 3) / 4);
    dim3 gAggS((N + 3) / 4, 4);        // x: 4 nodes/block, y: feature slice
    dim3 one(1);

    // --- detect formats; one-time weight splits; bucketed CSR build ---
    detect_kernel<<<one, tb, 0, stream>>>(ei, (const unsigned short*)ew,
                                          (const unsigned short*)x, flags);
    wsplit_kernel<<<dim3(64), tb, 0, stream>>>(W1, flags, w1hi, w1lo,
                                               64 * 256, 64 * 256);
    wsplit_kernel<<<dim3(16), tb, 0, stream>>>(W2, flags, w2hi, w2lo,
                                               64 * 64, 64 * 64);
    wsplit_kernel<<<dim3(4), tb, 0, stream>>>(W3, flags, w3hi, w3lo,
                                              10 * 64, 16 * 64);
    ones_kernel<<<gE4, tb, 0, stream>>>(ew, flags, E);
    khist_kernel<<<dim3(PB), tb512, 0, stream>>>(ei, flags, ghist, E, N, NB, chunk);
    koff1_kernel<<<dim3(NB), tb512, 0, stream>>>(ghist, btot, NB);
    koff2_kernel<<<one, tb, 0, stream>>>(btot, bstart, row_ptr, NB, N, E);
    kscatter_kernel<<<dim3(PB), tb512, 0, stream>>>(ei, ew, flags, ghist, bstart,
                                                    ebuf, wbuf, E, N, NB, chunk);
    kcsr_a_kernel<<<dim3(NB), tb512, 0, stream>>>(ebuf, wbuf, flags, bstart, btot,
                                                  row_ptr, dinv, N);
    kcsr_b_kernel<<<dim3(NB), tb512, 0, stream>>>(ebuf, wbuf, flags, bstart, btot,
                                                  row_ptr, dinv, csr_pack, N);

    // --- Layer 1: h1 = X*W1^T (slice-major) ; a1 = relu(S h1 + b1) ---
    gemm1_kernel<<<gG, tb, 0, stream>>>(x, w1hi, w1lo, flags, bufA, N, 256);
    agg64s_kernel<<<gAggS, tb, 0, stream>>>(bufA, b1, flags, row_ptr, csr_pack,
                                            bufB, N, 1);
    // --- Layer 2 ---
    gemm2_kernel<<<gG, tb, 0, stream>>>(bufB, w2hi, w2lo, flags, bufA, N);
    agg64s_kernel<<<gAggS, tb, 0, stream>>>(bufA, b2, flags, row_ptr, csr_pack,
                                            bufB, N, 1);
    // --- Layer 3 ---
    gemm3_kernel<<<gG, tb, 0, stream>>>(bufB, w3hi, w3lo, flags, h3buf, N);
    agg16_kernel<<<gAgg, tb, 0, stream>>>(h3buf, b3, flags, row_ptr, csr_pack,
                                          d_out, N);
}

// Round 10
// 590.870 us; speedup vs baseline: 1.4158x; 1.2525x over previous
//
#include <hip/hip_runtime.h>
#include <stddef.h>

typedef __attribute__((ext_vector_type(8))) short bf16x8;   // MFMA A/B frag
typedef __attribute__((ext_vector_type(4))) float f32x4;    // MFMA C/D frag
typedef __attribute__((ext_vector_type(8))) float f32x8;    // 32B fp32 load

#define NPB 512            // nodes per bucket (power of 2: bucket = c >> 9)
#define PB  512            // scatter blocks

// ---------------------------------------------------------------------------
// Manual bf16 <-> fp32 (storage type = unsigned short)
// ---------------------------------------------------------------------------
__device__ inline float bf2f(unsigned short u) {
    unsigned int v = ((unsigned int)u) << 16;
    float f;
    __builtin_memcpy(&f, &v, 4);
    return f;
}
__device__ inline unsigned short f2bf(float f) {
    unsigned int v;
    __builtin_memcpy(&v, &f, 4);
    unsigned int r = (v + 0x7FFFu + ((v >> 16) & 1u)) >> 16;   // RNE
    return (unsigned short)r;
}
__device__ inline float feat(const void* p, long long idx, int isbf) {
    if (isbf) return bf2f(((const unsigned short*)p)[idx]);
    return ((const float*)p)[idx];
}
__device__ inline int clampi(int v, int lo, int hi) {
    return v < lo ? lo : (v > hi ? hi : v);
}

// ---------------------------------------------------------------------------
// Format detection. flags[0]=edge_index int64; flags[1]=edge_weight bf16;
// flags[2]=features bf16; flags[3]=all edge_weights == 1.0.
// ---------------------------------------------------------------------------
__global__ void detect_kernel(const int* ei, const unsigned short* ew16,
                              const unsigned short* x16, int* flags) {
    __shared__ int s_is64, s_pass;
    if (threadIdx.x == 0) { s_is64 = 1; s_pass = 0; }
    __syncthreads();
    int t = threadIdx.x;
    if (t < 128 && ei[2 * t + 1] != 0) atomicAnd(&s_is64, 0);
    if (t < 64) {
        unsigned short h = x16[t];
        unsigned int expf = (h >> 7) & 0xFF;
        if (h == 0 || (expf >= 112 && expf <= 142)) atomicAdd(&s_pass, 1);
    }
    __syncthreads();
    if (t == 0) {
        flags[0] = s_is64;
        flags[1] = (ew16[0] == 0x3F80) ? 1 : 0;
        flags[2] = (s_pass >= 56) ? 1 : 0;
        flags[3] = 1;
    }
}

__global__ void ones_kernel(const void* ew, int* flags, int E) {
    int i = blockIdx.x * blockDim.x + threadIdx.x;
    int wbf = flags[1];
    int b = i * 4;
    int lim = b + 4 < E ? b + 4 : E;
    bool bad = false;
    for (int k = b; k < lim; k++)
        if (feat(ew, k, wbf) != 1.0f) bad = true;
    if (bad) atomicAnd(&flags[3], 0);
}

__global__ void sentinel_kernel(unsigned short* outp, int n, float val) {
    int i = blockIdx.x * blockDim.x + threadIdx.x;
    if (i < n) outp[i] = f2bf(val);
}

// ---------------------------------------------------------------------------
// One-time weight split: W (fp32 or bf16) -> (Whi, Wlo) bf16 pair.
// fp32: v ~= hi + lo; bf16 input: hi = v, lo = 0. Zero-pads to n_out.
// ---------------------------------------------------------------------------
__global__ void wsplit_kernel(const void* W, const int* flags, unsigned short* hi,
                              unsigned short* lo, int n_in, int n_out) {
    int i = blockIdx.x * blockDim.x + threadIdx.x;
    if (i >= n_out) return;
    if (i >= n_in) { hi[i] = 0; lo[i] = 0; return; }
    if (flags[2]) {
        hi[i] = ((const unsigned short*)W)[i];
        lo[i] = 0;
    } else {
        float v = ((const float*)W)[i];
        unsigned short h = f2bf(v);
        hi[i] = h;
        lo[i] = f2bf(v - bf2f(h));
    }
}

// ---------------------------------------------------------------------------
// Bucketed CSR build (atomic-light; all heavy writes locality-grouped)
// ---------------------------------------------------------------------------
// K1: per-block bucket histograms (LDS atomics only)
__global__ __launch_bounds__(512) void khist_kernel(const int* ei, const int* flags,
                                                    int* ghist, int E, int n,
                                                    int NB, int chunk) {
    __shared__ int hist[256];
    int blk = blockIdx.x;
    for (int i = threadIdx.x; i < NB; i += blockDim.x) hist[i] = 0;
    __syncthreads();
    int is64 = flags[0];
    int e0 = blk * chunk;
    int e1 = e0 + chunk < E ? e0 + chunk : E;
    for (int e = e0 + (int)threadIdx.x; e < e1; e += blockDim.x) {
        int c = is64 ? ei[2 * (E + e)] : ei[E + e];
        c = clampi(c, 0, n - 1);
        atomicAdd(&hist[c >> 9], 1);
    }
    __syncthreads();
    for (int i = threadIdx.x; i < NB; i += blockDim.x) ghist[blk * NB + i] = hist[i];
}

// K2: per-bucket exclusive scan over the PB block histograms (in place) + totals
__global__ __launch_bounds__(512) void koff1_kernel(int* ghist, int* btot, int NB) {
    __shared__ int s[512];
    int b = blockIdx.x;
    int t = threadIdx.x;
    int v = ghist[t * NB + b];
    s[t] = v;
    __syncthreads();
    for (int off = 1; off < 512; off <<= 1) {
        int add = (t >= off) ? s[t - off] : 0;
        __syncthreads();
        s[t] += add;
        __syncthreads();
    }
    ghist[t * NB + b] = s[t] - v;              // exclusive
    if (t == 511) btot[b] = s[511];
}

// K3: scan bucket totals -> bstart; write row_ptr[N] = E
__global__ __launch_bounds__(256) void koff2_kernel(const int* btot, int* bstart,
                                                    int* row_ptr, int NB, int N, int E) {
    __shared__ int s[256];
    int t = threadIdx.x;
    int v = (t < NB) ? btot[t] : 0;
    s[t] = v;
    __syncthreads();
    for (int off = 1; off < 256; off <<= 1) {
        int add = (t >= off) ? s[t - off] : 0;
        __syncthreads();
        s[t] += add;
        __syncthreads();
    }
    if (t < NB) bstart[t] = s[t] - v;
    if (t == 0) row_ptr[N] = E;
}

// K4: scatter edges into bucket-grouped ebuf (pack: c_local<<17 | r), deterministic
// offsets (no global atomics). wbuf written only on the general-weight path.
__global__ __launch_bounds__(512) void kscatter_kernel(const int* ei, const void* ew,
                                                       const int* flags, const int* ghist,
                                                       const int* bstart,
                                                       unsigned int* ebuf, float* wbuf,
                                                       int E, int n, int NB, int chunk) {
    __shared__ int cur[256];
    int blk = blockIdx.x;
    for (int i = threadIdx.x; i < NB; i += blockDim.x)
        cur[i] = ghist[blk * NB + i] + bstart[i];
    __syncthreads();
    int is64 = flags[0], wbf = flags[1], ones = flags[3];
    int e0 = blk * chunk;
    int e1 = e0 + chunk < E ? e0 + chunk : E;
    for (int e = e0 + (int)threadIdx.x; e < e1; e += blockDim.x) {
        int r = is64 ? ei[2 * e] : ei[e];
        int c = is64 ? ei[2 * (E + e)] : ei[E + e];
        r = clampi(r, 0, n - 1);
        c = clampi(c, 0, n - 1);
        int b = c >> 9;
        int pos = atomicAdd(&cur[b], 1);       // LDS atomic
        ebuf[pos] = ((unsigned int)(c & 511) << 17) | (unsigned int)r;
        if (!ones) wbuf[pos] = feat(ew, e, wbf);
    }
}

// K5: per-bucket node counts -> row_ptr + dinv (no global atomics)
__global__ __launch_bounds__(512) void kcsr_a_kernel(const unsigned int* ebuf,
                                                     const float* wbuf, const int* flags,
                                                     const int* bstart, const int* btot,
                                                     int* row_ptr, float* dinv, int N) {
    __shared__ int cnt[512];
    __shared__ int pre[512];
    __shared__ float wsum[512];
    int b = blockIdx.x;
    int t = threadIdx.x;
    int ones = flags[3];
    cnt[t] = 0;
    wsum[t] = 0.f;
    __syncthreads();
    int bs = bstart[b];
    int be = bs + btot[b];
    for (int i = bs + t; i < be; i += 512) {
        unsigned int p = ebuf[i];
        int cl = (int)(p >> 17);
        atomicAdd(&cnt[cl], 1);
        if (!ones) atomicAdd(&wsum[cl], wbuf[i]);
    }
    __syncthreads();
    int v = cnt[t];
    pre[t] = v;
    __syncthreads();
    for (int off = 1; off < 512; off <<= 1) {
        int add = (t >= off) ? pre[t - off] : 0;
        __syncthreads();
        pre[t] += add;
        __syncthreads();
    }
    int node = b * NPB + t;
    if (node < N) {
        row_ptr[node] = bs + pre[t] - v;
        float d = ones ? (float)v : wsum[t];
        dinv[node] = (d > 0.f) ? rsqrtf(fmaxf(d, 1e-12f)) : 0.f;
    }
}

// K6: per-bucket placement + norm -> csr_pack (int2: src, norm). Writes land in
// the bucket's contiguous CSR region (single-block local -> merged in L2).
__global__ __launch_bounds__(512) void kcsr_b_kernel(const unsigned int* ebuf,
                                                     const float* wbuf, const int* flags,
                                                     const int* bstart, const int* btot,
                                                     const int* row_ptr, const float* dinv,
                                                     int2* csr_pack, int N) {
    __shared__ int cur[512];
    __shared__ float dloc[512];
    int b = blockIdx.x;
    int t = threadIdx.x;
    int ones = flags[3];
    int node = b * NPB + t;
    cur[t] = (node < N) ? row_ptr[node] : 0;
    dloc[t] = (node < N) ? dinv[node] : 0.f;
    __syncthreads();
    int bs = bstart[b];
    int be = bs + btot[b];
    for (int i = bs + t; i < be; i += 512) {
        unsigned int p = ebuf[i];
        int cl = (int)(p >> 17);
        int r = (int)(p & 0x1FFFFu);
        float w = ones ? 1.0f : wbuf[i];
        float nv = dinv[r] * w * dloc[cl];
        int pos = atomicAdd(&cur[cl], 1);      // LDS atomic holding global pos
        csr_pack[pos] = make_int2(r, __float_as_int(nv));
    }
}

// ---------------------------------------------------------------------------
// In-register fp32 -> (bf16 hi, bf16 lo) split: v ~= hi + lo to ~2^-17 rel.
// ---------------------------------------------------------------------------
__device__ inline void split8v(f32x8 v, bf16x8& hi, bf16x8& lo) {
    for (int i = 0; i < 8; i++) {
        float f = v[i];
        unsigned short h = f2bf(f);
        hi[i] = (short)h;
        lo[i] = (short)f2bf(f - bf2f(h));
    }
}

// ---------------------------------------------------------------------------
// GEMM layer 1: C[M,64](bf16) = A[M,K] * W[64,K]^T, ROW-MAJOR out (round-3 cfg).
// Block = 64 rows (4 waves x 16-row tile); wave computes 16x64 via 4 col-frags.
// ---------------------------------------------------------------------------
__global__ __launch_bounds__(256) void gemm1_kernel(const void* A,
                             const unsigned short* Whi, const unsigned short* Wlo,
                             const int* flags, unsigned short* C, int M, int K) {
    int wave = threadIdx.x >> 6;
    int l = threadIdx.x & 63;
    int m = l & 15;
    int quad = l >> 4;
    int row0 = blockIdx.x * 64 + wave * 16;
    bool arow_ok = (row0 + m) < M;
    int fb = flags[2];
    f32x4 acc[4];
    #pragma unroll
    for (int n = 0; n < 4; n++) acc[n] = (f32x4){0.f, 0.f, 0.f, 0.f};
    bf16x8 zf = {0, 0, 0, 0, 0, 0, 0, 0};
    long long abase = (long long)(row0 + m) * K + quad * 8;
    if (fb) {
        const short* As = (const short*)A;
        #pragma unroll 4
        for (int k0 = 0; k0 < K; k0 += 32) {
            bf16x8 a = arow_ok ? *(const bf16x8*)(As + abase + k0) : zf;
            #pragma unroll
            for (int n = 0; n < 4; n++) {
                const unsigned short* wp = Whi + (long long)(n * 16 + m) * K + k0 + quad * 8;
                bf16x8 b = *(const bf16x8*)wp;
                acc[n] = __builtin_amdgcn_mfma_f32_16x16x32_bf16(a, b, acc[n], 0, 0, 0);
            }
        }
    } else {
        const float* Af = (const float*)A;
        #pragma unroll 2
        for (int k0 = 0; k0 < K; k0 += 32) {
            bf16x8 ah = zf, al = zf;
            if (arow_ok) {
                f32x8 av = *(const f32x8*)(Af + abase + k0);
                split8v(av, ah, al);
            }
            #pragma unroll
            for (int n = 0; n < 4; n++) {
                long long widx = (long long)(n * 16 + m) * K + k0 + quad * 8;
                bf16x8 wh = *(const bf16x8*)(Whi + widx);
                bf16x8 wl = *(const bf16x8*)(Wlo + widx);
                acc[n] = __builtin_amdgcn_mfma_f32_16x16x32_bf16(ah, wh, acc[n], 0, 0, 0);
                acc[n] = __builtin_amdgcn_mfma_f32_16x16x32_bf16(al, wh, acc[n], 0, 0, 0);
                acc[n] = __builtin_amdgcn_mfma_f32_16x16x32_bf16(ah, wl, acc[n], 0, 0, 0);
            }
        }
    }
    #pragma unroll
    for (int n = 0; n < 4; n++) {
        #pragma unroll
        for (int r = 0; r < 4; r++) {
            int row = row0 + quad * 4 + r;
            if (row < M) C[(long long)row * 64 + n * 16 + m] = f2bf(acc[n][r]);
        }
    }
}

// GEMM 2: A is bf16 [M,64] (internal buffer); ROW-MAJOR output.
__global__ __launch_bounds__(256) void gemm2_kernel(const unsigned short* A,
                             const unsigned short* Whi, const unsigned short* Wlo,
                             const int* flags, unsigned short* C, int M) {
    int wave = threadIdx.x >> 6;
    int l = threadIdx.x & 63;
    int m = l & 15;
    int quad = l >> 4;
    int row0 = blockIdx.x * 64 + wave * 16;
    bool arow_ok = (row0 + m) < M;
    int fb = flags[2];
    f32x4 acc[4];
    #pragma unroll
    for (int n = 0; n < 4; n++) acc[n] = (f32x4){0.f, 0.f, 0.f, 0.f};
    bf16x8 zf = {0, 0, 0, 0, 0, 0, 0, 0};
    const short* As = (const short*)A;
    long long abase = (long long)(row0 + m) * 64 + quad * 8;
    #pragma unroll
    for (int k0 = 0; k0 < 64; k0 += 32) {
        bf16x8 a = arow_ok ? *(const bf16x8*)(As + abase + k0) : zf;
        #pragma unroll
        for (int n = 0; n < 4; n++) {
            long long widx = (long long)(n * 16 + m) * 64 + k0 + quad * 8;
            bf16x8 wh = *(const bf16x8*)(Whi + widx);
            acc[n] = __builtin_amdgcn_mfma_f32_16x16x32_bf16(a, wh, acc[n], 0, 0, 0);
            if (!fb) {
                bf16x8 wl = *(const bf16x8*)(Wlo + widx);
                acc[n] = __builtin_amdgcn_mfma_f32_16x16x32_bf16(a, wl, acc[n], 0, 0, 0);
            }
        }
    }
    #pragma unroll
    for (int n = 0; n < 4; n++) {
        #pragma unroll
        for (int r = 0; r < 4; r++) {
            int row = row0 + quad * 4 + r;
            if (row < M) C[(long long)row * 64 + n * 16 + m] = f2bf(acc[n][r]);
        }
    }
}

// GEMM 3: [M,64] x W3[10,64]^T -> [M,16] bf16, zero-padded (W3 rows 10..15 = 0).
__global__ __launch_bounds__(256) void gemm3_kernel(const unsigned short* A,
                             const unsigned short* Whi, const unsigned short* Wlo,
                             const int* flags, unsigned short* C, int M) {
    int wave = threadIdx.x >> 6;
    int l = threadIdx.x & 63;
    int m = l & 15;
    int quad = l >> 4;
    int row0 = blockIdx.x * 64 + wave * 16;
    bool arow_ok = (row0 + m) < M;
    int fb = flags[2];
    f32x4 acc = {0.f, 0.f, 0.f, 0.f};
    bf16x8 zf = {0, 0, 0, 0, 0, 0, 0, 0};
    const short* As = (const short*)A;
    long long abase = (long long)(row0 + m) * 64 + quad * 8;
    #pragma unroll
    for (int k0 = 0; k0 < 64; k0 += 32) {
        bf16x8 a = arow_ok ? *(const bf16x8*)(As + abase + k0) : zf;
        long long widx = (long long)m * 64 + k0 + quad * 8;
        bf16x8 wh = *(const bf16x8*)(Whi + widx);
        acc = __builtin_amdgcn_mfma_f32_16x16x32_bf16(a, wh, acc, 0, 0, 0);
        if (!fb) {
            bf16x8 wl = *(const bf16x8*)(Wlo + widx);
            acc = __builtin_amdgcn_mfma_f32_16x16x32_bf16(a, wl, acc, 0, 0, 0);
        }
    }
    #pragma unroll
    for (int r = 0; r < 4; r++) {
        int row = row0 + quad * 4 + r;
        if (row < M) C[(long long)row * 16 + m] = f2bf(acc[r]);
    }
}

// ---------------------------------------------------------------------------
// agg64: wave per node; lane (g=l>>3 edge slot, j=l&7 feature octet).
// Request-rate-bound (~70G scattered req/s measured r3/r9). Unroll-by-2:
// two independent cp+gather pairs in flight per iter (~2x per-wave MLP) at
// ~32 VGPR -- occupancy preserved via __launch_bounds__(256,8) (r4's x8
// unroll at 48 VGPR halved occupancy and lost; x2 keeps the TLP).
// ---------------------------------------------------------------------------
__global__ __launch_bounds__(256, 8) void agg64_kernel(const unsigned short* h,
                             const void* bias, const int* flags, const int* row_ptr,
                             const int2* cp, unsigned short* outp, int n, int do_relu) {
    int l = threadIdx.x & 63;
    int node = blockIdx.x * 4 + (int)(threadIdx.x >> 6);
    if (node >= n) return;
    int g = l >> 3;
    int j = l & 7;
    int beg = row_ptr[node];
    int end = row_ptr[node + 1];
    float a0 = 0.f, a1 = 0.f, a2 = 0.f, a3 = 0.f;
    float a4 = 0.f, a5 = 0.f, a6 = 0.f, a7 = 0.f;
    int e = beg;
    for (; e + 16 <= end; e += 16) {
        int2 p0 = cp[e + g];
        int2 p1 = cp[e + 8 + g];
        uint4 r0 = *(const uint4*)(h + (long long)p0.x * 64 + j * 8);
        uint4 r1 = *(const uint4*)(h + (long long)p1.x * 64 + j * 8);
        float nv0 = __int_as_float(p0.y);
        float nv1 = __int_as_float(p1.y);
        a0 += nv0 * __uint_as_float(r0.x << 16);
        a1 += nv0 * __uint_as_float(r0.x & 0xFFFF0000u);
        a2 += nv0 * __uint_as_float(r0.y << 16);
        a3 += nv0 * __uint_as_float(r0.y & 0xFFFF0000u);
        a4 += nv0 * __uint_as_float(r0.z << 16);
        a5 += nv0 * __uint_as_float(r0.z & 0xFFFF0000u);
        a6 += nv0 * __uint_as_float(r0.w << 16);
        a7 += nv0 * __uint_as_float(r0.w & 0xFFFF0000u);
        a0 += nv1 * __uint_as_float(r1.x << 16);
        a1 += nv1 * __uint_as_float(r1.x & 0xFFFF0000u);
        a2 += nv1 * __uint_as_float(r1.y << 16);
        a3 += nv1 * __uint_as_float(r1.y & 0xFFFF0000u);
        a4 += nv1 * __uint_as_float(r1.z << 16);
        a5 += nv1 * __uint_as_float(r1.z & 0xFFFF0000u);
        a6 += nv1 * __uint_as_float(r1.w << 16);
        a7 += nv1 * __uint_as_float(r1.w & 0xFFFF0000u);
    }
    for (; e < end; e += 8) {
        int ee = e + g;
        if (ee < end) {
            int2 p = cp[ee];
            float nv = __int_as_float(p.y);
            uint4 raw = *(const uint4*)(h + (long long)p.x * 64 + j * 8);
            a0 += nv * __uint_as_float(raw.x << 16);
            a1 += nv * __uint_as_float(raw.x & 0xFFFF0000u);
            a2 += nv * __uint_as_float(raw.y << 16);
            a3 += nv * __uint_as_float(raw.y & 0xFFFF0000u);
            a4 += nv * __uint_as_float(raw.z << 16);
            a5 += nv * __uint_as_float(raw.z & 0xFFFF0000u);
            a6 += nv * __uint_as_float(raw.w << 16);
            a7 += nv * __uint_as_float(raw.w & 0xFFFF0000u);
        }
    }
    for (int mask = 8; mask <= 32; mask <<= 1) {
        a0 += __shfl_xor(a0, mask);
        a1 += __shfl_xor(a1, mask);
        a2 += __shfl_xor(a2, mask);
        a3 += __shfl_xor(a3, mask);
        a4 += __shfl_xor(a4, mask);
        a5 += __shfl_xor(a5, mask);
        a6 += __shfl_xor(a6, mask);
        a7 += __shfl_xor(a7, mask);
    }
    if (g == 0) {
        int fb = flags[2];
        float v0 = a0 + feat(bias, j * 8 + 0, fb);
        float v1 = a1 + feat(bias, j * 8 + 1, fb);
        float v2 = a2 + feat(bias, j * 8 + 2, fb);
        float v3 = a3 + feat(bias, j * 8 + 3, fb);
        float v4 = a4 + feat(bias, j * 8 + 4, fb);
        float v5 = a5 + feat(bias, j * 8 + 5, fb);
        float v6 = a6 + feat(bias, j * 8 + 6, fb);
        float v7 = a7 + feat(bias, j * 8 + 7, fb);
        if (do_relu) {
            v0 = fmaxf(v0, 0.f); v1 = fmaxf(v1, 0.f);
            v2 = fmaxf(v2, 0.f); v3 = fmaxf(v3, 0.f);
            v4 = fmaxf(v4, 0.f); v5 = fmaxf(v5, 0.f);
            v6 = fmaxf(v6, 0.f); v7 = fmaxf(v7, 0.f);
        }
        uint4 pk;
        pk.x = (unsigned int)f2bf(v0) | ((unsigned int)f2bf(v1) << 16);
        pk.y = (unsigned int)f2bf(v2) | ((unsigned int)f2bf(v3) << 16);
        pk.z = (unsigned int)f2bf(v4) | ((unsigned int)f2bf(v5) << 16);
        pk.w = (unsigned int)f2bf(v6) | ((unsigned int)f2bf(v7) << 16);
        *(uint4*)(outp + (long long)node * 64 + j * 8) = pk;
    }
}

// ---------------------------------------------------------------------------
// agg16: final aggregation over padded [N,16] bf16 h3 (only cols 0..9 nonzero).
// Wave per node; lane (g=l>>2: 16 edge slots, j=l&3: uint2 = 4 bf16 = 8B).
// Table (3.2MB) L2-resident.
// ---------------------------------------------------------------------------
__global__ void agg16_kernel(const unsigned short* h, const void* bias,
                             const int* flags, const int* row_ptr,
                             const int2* cp, void* outp, int n) {
    int l = threadIdx.x & 63;
    int node = blockIdx.x * 4 + (int)(threadIdx.x >> 6);
    if (node >= n) return;
    int g = l >> 2;          // edge slot 0..15
    int j = l & 3;           // feature quad
    int beg = row_ptr[node];
    int end = row_ptr[node + 1];
    float a0 = 0.f, a1 = 0.f, a2 = 0.f, a3 = 0.f;
    for (int e = beg; e < end; e += 16) {
        int ee = e + g;
        if (ee < end) {
            int2 p = cp[ee];
            float nv = __int_as_float(p.y);
            uint2 raw = *(const uint2*)(h + (long long)p.x * 16 + j * 4);
            a0 += nv * __uint_as_float(raw.x << 16);
            a1 += nv * __uint_as_float(raw.x & 0xFFFF0000u);
            a2 += nv * __uint_as_float(raw.y << 16);
            a3 += nv * __uint_as_float(raw.y & 0xFFFF0000u);
        }
    }
    for (int mask = 4; mask <= 32; mask <<= 1) {
        a0 += __shfl_xor(a0, mask);
        a1 += __shfl_xor(a1, mask);
        a2 += __shfl_xor(a2, mask);
        a3 += __shfl_xor(a3, mask);
    }
    if (g == 0) {
        int fb = flags[2];
        float v[4] = {a0, a1, a2, a3};
        #pragma unroll
        for (int i = 0; i < 4; i++) {
            int f = j * 4 + i;
            if (f < 10) {
                float o = v[i] + feat(bias, f, fb);
                if (fb) ((unsigned short*)outp)[(long long)node * 10 + f] = f2bf(o);
                else    ((float*)outp)[(long long)node * 10 + f] = o;
            }
        }
    }
}

// ---------------------------------------------------------------------------
extern "C" void kernel_launch(void* const* d_in, const int* in_sizes, int n_in,
                              void* d_out, int out_size, void* d_ws, size_t ws_size,
                              hipStream_t stream) {
    const void* x  = d_in[0];
    const int*  ei = (const int*)d_in[1];
    const void* ew = d_in[2];
    const void* W1 = d_in[3];
    const void* b1 = d_in[4];
    const void* W2 = d_in[5];
    const void* b2 = d_in[6];
    const void* W3 = d_in[7];
    const void* b3 = d_in[8];

    const int N = in_sizes[0] / 256;   // 100000
    const int E = in_sizes[1] / 2;     // 3200000
    const int TB = 256;
    const int NB = (N + NPB - 1) / NPB;            // 196 buckets
    const int chunk = (E + PB - 1) / PB;           // 6250 edges/block

    size_t off = 0;
    size_t o_flags = off; off += 16;
    size_t o_ghist = off; off += (size_t)PB * NB * 4; off = (off + 15) & ~(size_t)15;
    size_t o_btot  = off; off += (size_t)NB * 4;
    size_t o_bst   = off; off += (size_t)NB * 4; off = (off + 15) & ~(size_t)15;
    size_t o_rp    = off; off += (size_t)(N + 1) * 4;
    size_t o_dinv  = off; off += (size_t)N * 4; off = (off + 15) & ~(size_t)15;
    size_t o_pack  = off; off += (size_t)E * 8;
    size_t o_bufA  = off; off += (size_t)N * 64 * 2;   // overlays wbuf (E*4)
    size_t o_bufB  = off; off += (size_t)N * 64 * 2;   // overlays ebuf (E*4)
    size_t o_h3    = off; off += (size_t)N * 16 * 2; off = (off + 15) & ~(size_t)15;
    size_t o_w1hi  = off; off += (size_t)64 * 256 * 2;
    size_t o_w1lo  = off; off += (size_t)64 * 256 * 2;
    size_t o_w2hi  = off; off += (size_t)64 * 64 * 2;
    size_t o_w2lo  = off; off += (size_t)64 * 64 * 2;
    size_t o_w3hi  = off; off += (size_t)16 * 64 * 2;
    size_t o_w3lo  = off; off += (size_t)16 * 64 * 2;
    size_t need = off;
    // overlay safety: E*4 must fit in N*64*2
    if (ws_size < need || (size_t)E * 4 > (size_t)N * 64 * 2) {
        sentinel_kernel<<<dim3((out_size + TB - 1) / TB), dim3(TB), 0, stream>>>(
            (unsigned short*)d_out, out_size, 250.0f);
        return;
    }
    char* ws = (char*)d_ws;
    int*   flags    = (int*)(ws + o_flags);
    int*   ghist    = (int*)(ws + o_ghist);
    int*   btot     = (int*)(ws + o_btot);
    int*   bstart   = (int*)(ws + o_bst);
    int*   row_ptr  = (int*)(ws + o_rp);
    float* dinv     = (float*)(ws + o_dinv);
    int2*  csr_pack = (int2*)(ws + o_pack);
    unsigned short* bufA  = (unsigned short*)(ws + o_bufA);
    unsigned short* bufB  = (unsigned short*)(ws + o_bufB);
    unsigned short* h3buf = (unsigned short*)(ws + o_h3);
    unsigned short* w1hi  = (unsigned short*)(ws + o_w1hi);
    unsigned short* w1lo  = (unsigned short*)(ws + o_w1lo);
    unsigned short* w2hi  = (unsigned short*)(ws + o_w2hi);
    unsigned short* w2lo  = (unsigned short*)(ws + o_w2lo);
    unsigned short* w3hi  = (unsigned short*)(ws + o_w3hi);
    unsigned short* w3lo  = (unsigned short*)(ws + o_w3lo);
    float*        wbuf = (float*)bufA;         // lifetime ends before gemm1
    unsigned int* ebuf = (unsigned int*)bufB;  // lifetime ends before agg #1

    dim3 tb(TB);
    dim3 tb512(512);
    dim3 gE4((E / 4 + TB - 1) / TB);
    dim3 gG((N + 63) / 64);
    dim3 gAgg((N + 3) / 4);
    dim3 one(1);

    // --- detect formats; one-time weight splits; bucketed CSR build ---
    detect_kernel<<<one, tb, 0, stream>>>(ei, (const unsigned short*)ew,
                                          (const unsigned short*)x, flags);
    wsplit_kernel<<<dim3(64), tb, 0, stream>>>(W1, flags, w1hi, w1lo,
                                               64 * 256, 64 * 256);
    wsplit_kernel<<<dim3(16), tb, 0, stream>>>(W2, flags, w2hi, w2lo,
                                               64 * 64, 64 * 64);
    wsplit_kernel<<<dim3(4), tb, 0, stream>>>(W3, flags, w3hi, w3lo,
                                              10 * 64, 16 * 64);
    ones_kernel<<<gE4, tb, 0, stream>>>(ew, flags, E);
    khist_kernel<<<dim3(PB), tb512, 0, stream>>>(ei, flags, ghist, E, N, NB, chunk);
    koff1_kernel<<<dim3(NB), tb512, 0, stream>>>(ghist, btot, NB);
    koff2_kernel<<<one, tb, 0, stream>>>(btot, bstart, row_ptr, NB, N, E);
    kscatter_kernel<<<dim3(PB), tb512, 0, stream>>>(ei, ew, flags, ghist, bstart,
                                                    ebuf, wbuf, E, N, NB, chunk);
    kcsr_a_kernel<<<dim3(NB), tb512, 0, stream>>>(ebuf, wbuf, flags, bstart, btot,
                                                  row_ptr, dinv, N);
    kcsr_b_kernel<<<dim3(NB), tb512, 0, stream>>>(ebuf, wbuf, flags, bstart, btot,
                                                  row_ptr, dinv, csr_pack, N);

    // --- Layer 1: h1 = X*W1^T ; a1 = relu(S h1 + b1) ---
    gemm1_kernel<<<gG, tb, 0, stream>>>(x, w1hi, w1lo, flags, bufA, N, 256);
    agg64_kernel<<<gAgg, tb, 0, stream>>>(bufA, b1, flags, row_ptr, csr_pack,
                                          bufB, N, 1);
    // --- Layer 2 ---
    gemm2_kernel<<<gG, tb, 0, stream>>>(bufB, w2hi, w2lo, flags, bufA, N);
    agg64_kernel<<<gAgg, tb, 0, stream>>>(bufA, b2, flags, row_ptr, csr_pack,
                                          bufB, N, 1);
    // --- Layer 3 ---
    gemm3_kernel<<<gG, tb, 0, stream>>>(bufB, w3hi, w3lo, flags, h3buf, N);
    agg16_kernel<<<gAgg, tb, 0, stream>>>(h3buf, b3, flags, row_ptr, csr_pack,
                                          d_out, N);
}